// Round 11
// baseline (40.446 us; speedup 1.0000x reference)
//
#include <hip/hip_runtime.h>
#include <hip/hip_fp16.h>

#define Hd    256
#define OUTD  10
#define DDEP  10
#define KSTR  12
#define TLEN  8192
#define NTHR  512
#define NBLK  256
#define TILE  2048

// Module-scope sync: zero-init at load, monotonic across replays (proven r9/r10).
// g_ticket: consumer arrivals (255/replay) -> gen = ticket/255.
// g_flag:   K publications (1/replay) -> wait for flag >= gen+1.
__device__ unsigned g_ticket, g_flag;

__device__ __forceinline__ int ph(int j) { return j + (j >> 5); }

// LDS float offsets:
//  [0, 32768)      W2h: W2 as fp16 half2 (128 KB), producer chain / yb transpose (conv, 22528)
//  [32768, 35328)  Vs[DDEP][256] chain history (producer)
//  [35328, 37888)  W3s (producer)
//  [37888, 38016)  Ks[10][12] (all blocks, persists into conv)
//  [38016, ...)    xs conv window (all blocks, staged early)
#define OFF_W2H 0
#define OFF_VS  32768
#define OFF_W3  35328
#define OFF_KS  37888
#define OFF_XS  38016
#define XS_LOG  (TILE + DDEP)
#define SMEM_FLOATS (OFF_XS + XS_LOG + (XS_LOG >> 5) + 4)   // 40142 fl = 160568 B < 160 KiB

__global__ __launch_bounds__(NTHR, 1) void fused_rnn_kernel(
    const float* __restrict__ x, const float* __restrict__ w1g,
    const float* __restrict__ W2, const float* __restrict__ W3,
    float* __restrict__ y, float* __restrict__ Kb)
{
    __shared__ float smem[SMEM_FLOATS];
    __shared__ unsigned sgen;
    float* yb  = smem;                 // conv transpose buffer (aliases W2h)
    float* Vs  = smem + OFF_VS;
    float* W3s = smem + OFF_W3;
    float* Ks  = smem + OFF_KS;
    float* xs  = smem + OFF_XS;
    unsigned* W2u = (unsigned*)(smem + OFF_W2H);

    const int tid = threadIdx.x;
    const int bid = blockIdx.x;
    const int b   = bid >> 2;
    const int t0  = (bid & 3) * TILE;
    const float* xb = x + b * TLEN;

    if (bid == 0) {
        // ================= producer: fp16-LDS-resident chain =================
        // Thread t owns rows {2rp, 2rp+1}, cols q*64..q*64+63 (rp=t>>2, q=t&3).
        // W2h granule (t, s, slot j) holds logical octet jj = j ^ (t&7):
        // cols q*64 + 8*jj .. +7 of row 2rp+s, as 4 u32 of half2.
        // -> chain reads at step k use slot k^(t&7): 8-way bank-quad spread.
        const int rp = tid >> 2, q = tid & 3, x7 = tid & 7;
        (void)rp; (void)q;

        // ---- stage W2 -> LDS fp16 (coalesced global float4 reads) ----
        const float4* W2v4 = (const float4*)W2;
        for (int g = tid; g < 16384; g += NTHR) {
            const float4 f = W2v4[g];
            const int row = g >> 6, c4 = g & 63;
            const int t  = (row >> 1) * 4 + (c4 >> 4);   // owner thread
            const int s  = row & 1;
            const int jj = (c4 >> 1) & 7;
            const int j  = jj ^ (t & 7);
            const int e  = (c4 & 1) * 2;
            __half2 h0 = __float22half2_rn(make_float2(f.x, f.y));
            __half2 h1 = __float22half2_rn(make_float2(f.z, f.w));
            uint2 pk = make_uint2(*(unsigned*)&h0, *(unsigned*)&h1);
            *(uint2*)&W2u[t * 64 + s * 32 + j * 4 + e] = pk;
        }

        for (int i = tid; i < OUTD * Hd; i += NTHR) W3s[i] = W3[i];
        if (tid < Hd) Vs[tid] = w1g[tid];
        for (int j = tid; j < XS_LOG; j += NTHR) {       // own conv tile (tile 0)
            const int g = t0 - DDEP + j;
            xs[ph(j)] = (g >= 0) ? xb[g] : 0.0f;
        }
        __syncthreads();

        // ---- chain: v_{d+1} = W2 * v_d (9 serial iterations, LDS+VALU only) ----
        const uint4* W2h4 = (const uint4*)(smem + OFF_W2H);
        #pragma unroll 1
        for (int d = 0; d < DDEP - 1; ++d) {
            const float4* vsrc = (const float4*)(Vs + d * Hd);
            float a0 = 0.f, a1 = 0.f;
            #pragma unroll
            for (int k = 0; k < 8; ++k) {
                const int j = k ^ x7;
                const uint4 h0 = W2h4[tid * 16 + j];
                const uint4 h1 = W2h4[tid * 16 + 8 + j];
                const float4 vA = vsrc[q * 16 + 2 * k];
                const float4 vB = vsrc[q * 16 + 2 * k + 1];
                const __half2* p0 = (const __half2*)&h0;
                const __half2* p1 = (const __half2*)&h1;
                float2 f;
                f = __half22float2(p0[0]); a0 = fmaf(f.x, vA.x, a0); a0 = fmaf(f.y, vA.y, a0);
                f = __half22float2(p0[1]); a0 = fmaf(f.x, vA.z, a0); a0 = fmaf(f.y, vA.w, a0);
                f = __half22float2(p0[2]); a0 = fmaf(f.x, vB.x, a0); a0 = fmaf(f.y, vB.y, a0);
                f = __half22float2(p0[3]); a0 = fmaf(f.x, vB.z, a0); a0 = fmaf(f.y, vB.w, a0);
                f = __half22float2(p1[0]); a1 = fmaf(f.x, vA.x, a1); a1 = fmaf(f.y, vA.y, a1);
                f = __half22float2(p1[1]); a1 = fmaf(f.x, vA.z, a1); a1 = fmaf(f.y, vA.w, a1);
                f = __half22float2(p1[2]); a1 = fmaf(f.x, vB.x, a1); a1 = fmaf(f.y, vB.y, a1);
                f = __half22float2(p1[3]); a1 = fmaf(f.x, vB.z, a1); a1 = fmaf(f.y, vB.w, a1);
            }
            a0 += __shfl_xor(a0, 1);  a0 += __shfl_xor(a0, 2);
            a1 += __shfl_xor(a1, 1);  a1 += __shfl_xor(a1, 2);
            if (q == 0)
                ((float2*)(Vs + (d + 1) * Hd))[rp] = make_float2(a0, a1);
            __syncthreads();
        }

        // ---- K[d][o] = W3[o] . v_d : wave w handles d = w and w+8 ----
        {
            const int w = tid >> 6, l = tid & 63;
            #pragma unroll
            for (int dd = 0; dd < 2; ++dd) {
                const int d = w + dd * 8;
                if (d < DDEP) {
                    const float4 vv = ((const float4*)(Vs + d * Hd))[l];
                    #pragma unroll
                    for (int o = 0; o < OUTD; ++o) {
                        const float4 wv = ((const float4*)(W3s + o * Hd))[l];
                        float p = fmaf(wv.x, vv.x,
                                  fmaf(wv.y, vv.y,
                                  fmaf(wv.z, vv.z, wv.w * vv.w)));
                        p += __shfl_xor(p, 1);  p += __shfl_xor(p, 2);
                        p += __shfl_xor(p, 4);  p += __shfl_xor(p, 8);
                        p += __shfl_xor(p, 16); p += __shfl_xor(p, 32);
                        if (l == 0) Ks[d * KSTR + o] = p;
                    }
                    if (l == 1) { Ks[d * KSTR + 10] = 0.f; Ks[d * KSTR + 11] = 0.f; }
                }
            }
        }
        __syncthreads();
        if (tid < DDEP * KSTR) Kb[tid] = Ks[tid];
        __syncthreads();                    // Kb stores drained before publish
        if (tid == 0) {
            __threadfence();                // release: K visible at coherent point
            __hip_atomic_fetch_add(&g_flag, 1u, __ATOMIC_RELEASE,
                                   __HIP_MEMORY_SCOPE_AGENT);
        }
        // falls through to conv; Ks live in LDS
    } else {
        // ================= consumers: stage x, then wait for K =================
        if (tid == 0)
            sgen = __hip_atomic_fetch_add(&g_ticket, 1u, __ATOMIC_RELAXED,
                                          __HIP_MEMORY_SCOPE_AGENT) / (NBLK - 1);
        for (int j = tid; j < XS_LOG; j += NTHR) {
            const int g = t0 - DDEP + j;
            xs[ph(j)] = (g >= 0) ? xb[g] : 0.0f;
        }
        __syncthreads();
        if (tid == 0) {
            const unsigned target = sgen + 1u;
            unsigned guard = 0;
            // RELAXED polling (no per-poll cache maintenance), one acquire at exit
            while (__hip_atomic_load(&g_flag, __ATOMIC_RELAXED,
                                     __HIP_MEMORY_SCOPE_AGENT) < target) {
                __builtin_amdgcn_s_sleep(8);
                if (++guard > 4000000u) break;      // fail loud, not hang
            }
            (void)__hip_atomic_load(&g_flag, __ATOMIC_ACQUIRE,
                                    __HIP_MEMORY_SCOPE_AGENT);
        }
        __syncthreads();
        if (tid < DDEP * KSTR) Ks[tid] = Kb[tid];
        __syncthreads();
    }

    // ================= causal FIR: 4 consecutive positions per thread =================
    const int ub = tid * 4;
    float acc[4][OUTD];
    #pragma unroll
    for (int i = 0; i < 4; ++i)
        #pragma unroll
        for (int o = 0; o < OUTD; ++o) acc[i][o] = 0.0f;

    float wn[4];
    #pragma unroll
    for (int i = 0; i < 4; ++i) wn[i] = xs[ph(ub + DDEP + i)];

    #pragma unroll
    for (int d = 0; d < DDEP; ++d) {
        const float4 kA = *(const float4*)&Ks[d * KSTR];
        const float4 kB = *(const float4*)&Ks[d * KSTR + 4];
        const float2 kC = *(const float2*)&Ks[d * KSTR + 8];
        #pragma unroll
        for (int i = 0; i < 4; ++i) {
            const float xv = wn[i];
            acc[i][0] = fmaf(kA.x, xv, acc[i][0]);
            acc[i][1] = fmaf(kA.y, xv, acc[i][1]);
            acc[i][2] = fmaf(kA.z, xv, acc[i][2]);
            acc[i][3] = fmaf(kA.w, xv, acc[i][3]);
            acc[i][4] = fmaf(kB.x, xv, acc[i][4]);
            acc[i][5] = fmaf(kB.y, xv, acc[i][5]);
            acc[i][6] = fmaf(kB.z, xv, acc[i][6]);
            acc[i][7] = fmaf(kB.w, xv, acc[i][7]);
            acc[i][8] = fmaf(kC.x, xv, acc[i][8]);
            acc[i][9] = fmaf(kC.y, xv, acc[i][9]);
        }
        const float nw = xs[ph(ub + DDEP - 1 - d)];
        wn[3] = wn[2]; wn[2] = wn[1]; wn[1] = wn[0]; wn[0] = nw;
    }

    // transpose via LDS (stride 11), then fully-coalesced float4 stores
    #pragma unroll
    for (int i = 0; i < 4; ++i)
        #pragma unroll
        for (int o = 0; o < OUTD; ++o)
            yb[(ub + i) * 11 + o] = acc[i][o];
    __syncthreads();

    float* yg = y + ((size_t)b * TLEN + t0) * OUTD;
    #pragma unroll
    for (int pass = 0; pass < 10; ++pass) {
        const int l = (pass * NTHR + tid) * 4;
        float4 v;
        v.x = yb[l     + (l    ) / 10];
        v.y = yb[l + 1 + (l + 1) / 10];
        v.z = yb[l + 2 + (l + 2) / 10];
        v.w = yb[l + 3 + (l + 3) / 10];
        *(float4*)(yg + l) = v;
    }
}

extern "C" void kernel_launch(void* const* d_in, const int* in_sizes, int n_in,
                              void* d_out, int out_size, void* d_ws, size_t ws_size,
                              hipStream_t stream)
{
    const float* x  = (const float*)d_in[0];   // (64, 8192)
    const float* w1 = (const float*)d_in[1];   // (256, 1) contiguous
    const float* W2 = (const float*)d_in[2];   // (256, 256)
    const float* W3 = (const float*)d_in[3];   // (10, 256)
    float* y  = (float*)d_out;
    float* Kb = (float*)d_ws;                  // 120 floats

    fused_rnn_kernel<<<NBLK, dim3(NTHR), 0, stream>>>(x, w1, W2, W3, y, Kb);
}

// Round 12
// 35.259 us; speedup vs baseline: 1.1471x; 1.1471x over previous
//
#include <hip/hip_runtime.h>

#define Hd    256
#define OUTD  10
#define DDEP  10
#define KSTR  12
#define TLEN  8192
#define NTHR  512
#define NBLK  256
#define TILE  2048

typedef __attribute__((ext_vector_type(8))) short bf16x8;
typedef __attribute__((ext_vector_type(4))) float f32x4;

// Module-scope sync: zero-init at load, monotonic across replays (proven r9-r11).
__device__ unsigned g_ticket, g_flag;

__device__ __forceinline__ int ph(int j) { return j + (j >> 5); }

// bf16 round-to-nearest-even helpers (no NaN in this data)
__device__ __forceinline__ unsigned bfr(float x) {
    unsigned u = __float_as_uint(x);
    return (u + 0x7FFFu + ((u >> 16) & 1u)) >> 16;
}
__device__ __forceinline__ unsigned bfpk(float lo, float hi) {
    unsigned uh = __float_as_uint(hi);
    unsigned h  = (uh + 0x7FFFu + ((uh >> 16) & 1u)) & 0xFFFF0000u;
    return bfr(lo) | h;
}

// LDS float offsets:
//  [0, 22528)   yb transpose buffer (conv). Block 0 pre-conv aliases:
//               Vs fp32 [10][256] @0, W3s @2560, Vs_bf (256 u32) @5120.
//  [22528,..)   Ks[10][12]; xs conv window after it.
#define OFF_VS   0
#define OFF_W3   2560
#define OFF_VBF  5120
#define OFF_KS   22528
#define OFF_XS   (OFF_KS + 128)
#define XS_LOG   (TILE + DDEP)
#define SMEM_FLOATS (OFF_XS + XS_LOG + (XS_LOG >> 5) + 4)   // ~99 KB

__global__ __launch_bounds__(NTHR, 1) void fused_rnn_kernel(
    const float* __restrict__ x, const float* __restrict__ w1g,
    const float* __restrict__ W2, const float* __restrict__ W3,
    float* __restrict__ y, float* __restrict__ Kb)
{
    __shared__ float smem[SMEM_FLOATS];
    __shared__ unsigned sgen;
    float* yb  = smem;
    float* Vs  = smem + OFF_VS;
    float* W3s = smem + OFF_W3;
    unsigned* Vbf = (unsigned*)(smem + OFF_VBF);   // [2][128] bf16-pair ping-pong
    float* Ks  = smem + OFF_KS;
    float* xs  = smem + OFF_XS;

    const int tid = threadIdx.x;
    const int bid = blockIdx.x;
    const int b   = bid >> 2;
    const int t0  = (bid & 3) * TILE;
    const float* xb = x + b * TLEN;

    if (bid == 0) {
        // ========== producer: MFMA chain, W2 bf16 A-frags resident in VGPRs ==========
        const int w = tid >> 6, l = tid & 63;
        const int m  = l & 15;            // row within 16-tile
        const int kb = (l >> 4) * 8;      // k-base within 32-chunk

        // A-frags: wave w owns rows [32w, 32w+32): 2 row-tiles x 8 k-tiles.
        bf16x8 Afr[2][8];
        #pragma unroll
        for (int rt = 0; rt < 2; ++rt) {
            const float* rp = W2 + (32 * w + 16 * rt + m) * Hd + kb;
            #pragma unroll
            for (int kt = 0; kt < 8; ++kt) {
                const float4 pa = *(const float4*)(rp + 32 * kt);
                const float4 pb = *(const float4*)(rp + 32 * kt + 4);
                Afr[rt][kt] = __builtin_bit_cast(bf16x8,
                    make_int4((int)bfpk(pa.x, pa.y), (int)bfpk(pa.z, pa.w),
                              (int)bfpk(pb.x, pb.y), (int)bfpk(pb.z, pb.w)));
            }
        }

        for (int i = tid; i < OUTD * Hd; i += NTHR) W3s[i] = W3[i];
        if (tid < Hd) Vs[tid] = w1g[tid];                       // fp32 v0
        if (tid < 128) Vbf[tid] = bfpk(w1g[2 * tid], w1g[2 * tid + 1]);  // bf16 v0
        for (int j = tid; j < XS_LOG; j += NTHR) {              // own conv tile
            const int g = t0 - DDEP + j;
            xs[ph(j)] = (g >= 0) ? xb[g] : 0.0f;
        }
        __syncthreads();

        // ---- chain: v_{d+1} = W2 * v_d, 9 serial MFMA iterations ----
        #pragma unroll 1
        for (int d = 0; d < DDEP - 1; ++d) {
            const unsigned* vbf = Vbf + (d & 1) * 128;
            bf16x8 Bfr[8];
            #pragma unroll
            for (int kt = 0; kt < 8; ++kt) {
                // broadcast read: 4 distinct addresses per wave; cols 1..15 of
                // the MFMA get replicated v values -> garbage we ignore.
                const int4 bu = *(const int4*)&vbf[kt * 16 + (l >> 4) * 4];
                Bfr[kt] = __builtin_bit_cast(bf16x8, bu);
            }
            f32x4 acc0 = {0.f, 0.f, 0.f, 0.f};
            f32x4 acc1 = {0.f, 0.f, 0.f, 0.f};
            #pragma unroll
            for (int kt = 0; kt < 8; ++kt) {
                acc0 = __builtin_amdgcn_mfma_f32_16x16x32_bf16(Afr[0][kt], Bfr[kt], acc0, 0, 0, 0);
                acc1 = __builtin_amdgcn_mfma_f32_16x16x32_bf16(Afr[1][kt], Bfr[kt], acc1, 0, 0, 0);
            }
            // C layout: col = lane&15, row = (lane>>4)*4 + reg (m89-verified).
            if ((l & 15) == 0) {
                const int g  = l >> 4;
                const int r0 = 32 * w + 4 * g;          // acc0 rows r0..r0+3
                const int r1 = r0 + 16;                 // acc1 rows
                *(f32x4*)&Vs[(d + 1) * Hd + r0] = acc0; // fp32 history (K-dots)
                *(f32x4*)&Vs[(d + 1) * Hd + r1] = acc1;
                unsigned* dst = Vbf + ((d + 1) & 1) * 128;
                *(uint2*)&dst[r0 >> 1] =
                    make_uint2(bfpk(acc0.x, acc0.y), bfpk(acc0.z, acc0.w));
                *(uint2*)&dst[r1 >> 1] =
                    make_uint2(bfpk(acc1.x, acc1.y), bfpk(acc1.z, acc1.w));
            }
            __syncthreads();
        }

        // ---- K[d][o] = W3[o] . v_d : wave w handles d = w and w+8 ----
        {
            #pragma unroll
            for (int dd = 0; dd < 2; ++dd) {
                const int d = w + dd * 8;
                if (d < DDEP) {
                    const float4 vv = ((const float4*)(Vs + d * Hd))[l];
                    #pragma unroll
                    for (int o = 0; o < OUTD; ++o) {
                        const float4 wv = ((const float4*)(W3s + o * Hd))[l];
                        float p = fmaf(wv.x, vv.x,
                                  fmaf(wv.y, vv.y,
                                  fmaf(wv.z, vv.z, wv.w * vv.w)));
                        p += __shfl_xor(p, 1);  p += __shfl_xor(p, 2);
                        p += __shfl_xor(p, 4);  p += __shfl_xor(p, 8);
                        p += __shfl_xor(p, 16); p += __shfl_xor(p, 32);
                        if (l == 0) Ks[d * KSTR + o] = p;
                    }
                    if (l == 1) { Ks[d * KSTR + 10] = 0.f; Ks[d * KSTR + 11] = 0.f; }
                }
            }
        }
        __syncthreads();
        if (tid < DDEP * KSTR) Kb[tid] = Ks[tid];
        __syncthreads();                    // Kb stores drained before publish
        if (tid == 0) {
            __threadfence();                // release
            __hip_atomic_fetch_add(&g_flag, 1u, __ATOMIC_RELEASE,
                                   __HIP_MEMORY_SCOPE_AGENT);
        }
        // falls through to conv; Ks live in LDS
    } else {
        // ========== consumers: stage x, then wait for K ==========
        if (tid == 0)
            sgen = __hip_atomic_fetch_add(&g_ticket, 1u, __ATOMIC_RELAXED,
                                          __HIP_MEMORY_SCOPE_AGENT) / (NBLK - 1);
        for (int j = tid; j < XS_LOG; j += NTHR) {
            const int g = t0 - DDEP + j;
            xs[ph(j)] = (g >= 0) ? xb[g] : 0.0f;
        }
        __syncthreads();
        if (tid == 0) {
            const unsigned target = sgen + 1u;
            unsigned guard = 0;
            while (__hip_atomic_load(&g_flag, __ATOMIC_RELAXED,
                                     __HIP_MEMORY_SCOPE_AGENT) < target) {
                __builtin_amdgcn_s_sleep(8);
                if (++guard > 4000000u) break;      // fail loud, not hang
            }
            (void)__hip_atomic_load(&g_flag, __ATOMIC_ACQUIRE,
                                    __HIP_MEMORY_SCOPE_AGENT);
        }
        __syncthreads();
        if (tid < DDEP * KSTR) Ks[tid] = Kb[tid];
        __syncthreads();
    }

    // ========== causal FIR: 4 consecutive positions per thread ==========
    const int ub = tid * 4;
    float acc[4][OUTD];
    #pragma unroll
    for (int i = 0; i < 4; ++i)
        #pragma unroll
        for (int o = 0; o < OUTD; ++o) acc[i][o] = 0.0f;

    float wn[4];
    #pragma unroll
    for (int i = 0; i < 4; ++i) wn[i] = xs[ph(ub + DDEP + i)];

    #pragma unroll
    for (int d = 0; d < DDEP; ++d) {
        const float4 kA = *(const float4*)&Ks[d * KSTR];
        const float4 kB = *(const float4*)&Ks[d * KSTR + 4];
        const float2 kC = *(const float2*)&Ks[d * KSTR + 8];
        #pragma unroll
        for (int i = 0; i < 4; ++i) {
            const float xv = wn[i];
            acc[i][0] = fmaf(kA.x, xv, acc[i][0]);
            acc[i][1] = fmaf(kA.y, xv, acc[i][1]);
            acc[i][2] = fmaf(kA.z, xv, acc[i][2]);
            acc[i][3] = fmaf(kA.w, xv, acc[i][3]);
            acc[i][4] = fmaf(kB.x, xv, acc[i][4]);
            acc[i][5] = fmaf(kB.y, xv, acc[i][5]);
            acc[i][6] = fmaf(kB.z, xv, acc[i][6]);
            acc[i][7] = fmaf(kB.w, xv, acc[i][7]);
            acc[i][8] = fmaf(kC.x, xv, acc[i][8]);
            acc[i][9] = fmaf(kC.y, xv, acc[i][9]);
        }
        const float nw = xs[ph(ub + DDEP - 1 - d)];
        wn[3] = wn[2]; wn[2] = wn[1]; wn[1] = wn[0]; wn[0] = nw;
    }

    // transpose via LDS (stride 11), then fully-coalesced float4 stores
    #pragma unroll
    for (int i = 0; i < 4; ++i)
        #pragma unroll
        for (int o = 0; o < OUTD; ++o)
            yb[(ub + i) * 11 + o] = acc[i][o];
    __syncthreads();

    float* yg = y + ((size_t)b * TLEN + t0) * OUTD;
    #pragma unroll
    for (int pass = 0; pass < 10; ++pass) {
        const int l2 = (pass * NTHR + tid) * 4;
        float4 v;
        v.x = yb[l2     + (l2    ) / 10];
        v.y = yb[l2 + 1 + (l2 + 1) / 10];
        v.z = yb[l2 + 2 + (l2 + 2) / 10];
        v.w = yb[l2 + 3 + (l2 + 3) / 10];
        *(float4*)(yg + l2) = v;
    }
}

extern "C" void kernel_launch(void* const* d_in, const int* in_sizes, int n_in,
                              void* d_out, int out_size, void* d_ws, size_t ws_size,
                              hipStream_t stream)
{
    const float* x  = (const float*)d_in[0];   // (64, 8192)
    const float* w1 = (const float*)d_in[1];   // (256, 1) contiguous
    const float* W2 = (const float*)d_in[2];   // (256, 256)
    const float* W3 = (const float*)d_in[3];   // (10, 256)
    float* y  = (float*)d_out;
    float* Kb = (float*)d_ws;                  // 120 floats

    fused_rnn_kernel<<<NBLK, dim3(NTHR), 0, stream>>>(x, w1, W2, W3, y, Kb);
}

// Round 13
// 27.500 us; speedup vs baseline: 1.4708x; 1.2821x over previous
//
#include <hip/hip_runtime.h>

#define Hd    256
#define OUTD  10
#define DDEP  10
#define KSTR  12
#define TLEN  8192
#define NTHR  512
#define NBLK  256
#define TILE  2048

typedef __attribute__((ext_vector_type(8))) short bf16x8;
typedef __attribute__((ext_vector_type(4))) float f32x4;

__device__ __forceinline__ int ph(int j) { return j + (j >> 5); }

// bf16 round-to-nearest-even helpers (no NaN in this data)
__device__ __forceinline__ unsigned bfr(float x) {
    unsigned u = __float_as_uint(x);
    return (u + 0x7FFFu + ((u >> 16) & 1u)) >> 16;
}
__device__ __forceinline__ unsigned bfpk(float lo, float hi) {
    unsigned uh = __float_as_uint(hi);
    unsigned h  = (uh + 0x7FFFu + ((uh >> 16) & 1u)) & 0xFFFF0000u;
    return bfr(lo) | h;
}

// LDS float/u32 offsets:
//  [0, 32768)      W2h: W2 bf16, [256 rows][128 u32 cols, XOR-swizzled].
//                  Dead after A-frag build; yb transpose (22528 f) aliases it.
//  [32768, 35328)  Vs fp32 [10][256] chain history
//  [35328, 37888)  W3s [10][256]
//  [37888, 38144)  Vbf [2][128] u32 bf16-pair ping-pong
//  [38144, 38272)  Ks [10][12] (+pad)
//  [38272, ...)    xs conv window (swizzled)
#define OFF_W2H 0
#define OFF_VS  32768
#define OFF_W3  35328
#define OFF_VBF 37888
#define OFF_KS  38144
#define OFF_XS  38272
#define XS_LOG  (TILE + DDEP)
#define SMEM_FLOATS (OFF_XS + XS_LOG + (XS_LOG >> 5) + 4)   // 40398 f = 161592 B

__global__ __launch_bounds__(NTHR, 1) void fused_rnn_kernel(
    const float* __restrict__ x, const float* __restrict__ w1g,
    const float* __restrict__ W2, const float* __restrict__ W3,
    float* __restrict__ y)
{
    __shared__ float smem[SMEM_FLOATS];
    float* yb  = smem;                               // aliases W2h (epilogue only)
    unsigned* W2u = (unsigned*)(smem + OFF_W2H);
    float* Vs  = smem + OFF_VS;
    float* W3s = smem + OFF_W3;
    unsigned* Vbf = (unsigned*)(smem + OFF_VBF);
    float* Ks  = smem + OFF_KS;
    float* xs  = smem + OFF_XS;

    const int tid = threadIdx.x;
    const int bid = blockIdx.x;
    const int b   = bid >> 2;
    const int t0  = (bid & 3) * TILE;
    const float* xb = x + b * TLEN;

    // ---- stage W2 -> bf16 LDS (coalesced float4 global reads, swizzled cols) ----
    const float4* W2v4 = (const float4*)W2;
    for (int g = tid; g < 16384; g += NTHR) {
        const float4 f = W2v4[g];
        const int row = g >> 6;
        const int c   = (g & 63) * 2;                // u32 col (even)
        const int phys = c ^ ((row & 7) << 2);       // XOR-swizzle bits 2..4
        *(uint2*)&W2u[row * 128 + phys] =
            make_uint2(bfpk(f.x, f.y), bfpk(f.z, f.w));
    }

    // ---- stage xs (swizzled), W3s, v0 (fp32 + bf16) ----
    for (int j = tid; j < XS_LOG; j += NTHR) {
        const int g = t0 - DDEP + j;
        xs[ph(j)] = (g >= 0) ? xb[g] : 0.0f;
    }
    for (int i = tid; i < OUTD * Hd; i += NTHR) W3s[i] = W3[i];
    if (tid < Hd) Vs[tid] = w1g[tid];
    if (tid < 128) Vbf[tid] = bfpk(w1g[2 * tid], w1g[2 * tid + 1]);
    __syncthreads();

    // ---- build A-frags from LDS: wave w owns rows [32w,32w+32) ----
    const int w = tid >> 6, l = tid & 63;
    bf16x8 Afr[2][8];
    #pragma unroll
    for (int rt = 0; rt < 2; ++rt) {
        const int row = 32 * w + 16 * rt + (l & 15);
        #pragma unroll
        for (int kt = 0; kt < 8; ++kt) {
            const int c    = kt * 16 + (l >> 4) * 4;       // u32 col, 4-aligned
            const int phys = c ^ ((row & 7) << 2);
            Afr[rt][kt] = __builtin_bit_cast(bf16x8,
                *(const int4*)&W2u[row * 128 + phys]);
        }
    }
    __syncthreads();       // W2h dead from here; yb may overwrite later

    // ---- chain: v_{d+1} = W2 * v_d, 9 serial MFMA iterations (r12-proven) ----
    #pragma unroll 1
    for (int d = 0; d < DDEP - 1; ++d) {
        const unsigned* vbf = Vbf + (d & 1) * 128;
        bf16x8 Bfr[8];
        #pragma unroll
        for (int kt = 0; kt < 8; ++kt) {
            const int4 bu = *(const int4*)&vbf[kt * 16 + (l >> 4) * 4];
            Bfr[kt] = __builtin_bit_cast(bf16x8, bu);
        }
        f32x4 acc0 = {0.f, 0.f, 0.f, 0.f};
        f32x4 acc1 = {0.f, 0.f, 0.f, 0.f};
        #pragma unroll
        for (int kt = 0; kt < 8; ++kt) {
            acc0 = __builtin_amdgcn_mfma_f32_16x16x32_bf16(Afr[0][kt], Bfr[kt], acc0, 0, 0, 0);
            acc1 = __builtin_amdgcn_mfma_f32_16x16x32_bf16(Afr[1][kt], Bfr[kt], acc1, 0, 0, 0);
        }
        // C layout: col = lane&15, row = (lane>>4)*4 + reg (m89-verified)
        if ((l & 15) == 0) {
            const int g  = l >> 4;
            const int r0 = 32 * w + 4 * g;
            const int r1 = r0 + 16;
            *(f32x4*)&Vs[(d + 1) * Hd + r0] = acc0;
            *(f32x4*)&Vs[(d + 1) * Hd + r1] = acc1;
            unsigned* dst = Vbf + ((d + 1) & 1) * 128;
            *(uint2*)&dst[r0 >> 1] =
                make_uint2(bfpk(acc0.x, acc0.y), bfpk(acc0.z, acc0.w));
            *(uint2*)&dst[r1 >> 1] =
                make_uint2(bfpk(acc1.x, acc1.y), bfpk(acc1.z, acc1.w));
        }
        __syncthreads();
    }

    // ---- K[d][o] = W3[o] . v_d : wave w handles d = w and w+8 ----
    {
        #pragma unroll
        for (int dd = 0; dd < 2; ++dd) {
            const int d = w + dd * 8;
            if (d < DDEP) {
                const float4 vv = ((const float4*)(Vs + d * Hd))[l];
                #pragma unroll
                for (int o = 0; o < OUTD; ++o) {
                    const float4 wv = ((const float4*)(W3s + o * Hd))[l];
                    float p = fmaf(wv.x, vv.x,
                              fmaf(wv.y, vv.y,
                              fmaf(wv.z, vv.z, wv.w * vv.w)));
                    p += __shfl_xor(p, 1);  p += __shfl_xor(p, 2);
                    p += __shfl_xor(p, 4);  p += __shfl_xor(p, 8);
                    p += __shfl_xor(p, 16); p += __shfl_xor(p, 32);
                    if (l == 0) Ks[d * KSTR + o] = p;
                }
                if (l == 1) { Ks[d * KSTR + 10] = 0.f; Ks[d * KSTR + 11] = 0.f; }
            }
        }
    }
    __syncthreads();

    // ---- causal FIR: 4 consecutive positions per thread ----
    const int ub = tid * 4;
    float acc[4][OUTD];
    #pragma unroll
    for (int i = 0; i < 4; ++i)
        #pragma unroll
        for (int o = 0; o < OUTD; ++o) acc[i][o] = 0.0f;

    float wn[4];
    #pragma unroll
    for (int i = 0; i < 4; ++i) wn[i] = xs[ph(ub + DDEP + i)];

    #pragma unroll
    for (int d = 0; d < DDEP; ++d) {
        const float4 kA = *(const float4*)&Ks[d * KSTR];
        const float4 kB = *(const float4*)&Ks[d * KSTR + 4];
        const float2 kC = *(const float2*)&Ks[d * KSTR + 8];
        #pragma unroll
        for (int i = 0; i < 4; ++i) {
            const float xv = wn[i];
            acc[i][0] = fmaf(kA.x, xv, acc[i][0]);
            acc[i][1] = fmaf(kA.y, xv, acc[i][1]);
            acc[i][2] = fmaf(kA.z, xv, acc[i][2]);
            acc[i][3] = fmaf(kA.w, xv, acc[i][3]);
            acc[i][4] = fmaf(kB.x, xv, acc[i][4]);
            acc[i][5] = fmaf(kB.y, xv, acc[i][5]);
            acc[i][6] = fmaf(kB.z, xv, acc[i][6]);
            acc[i][7] = fmaf(kB.w, xv, acc[i][7]);
            acc[i][8] = fmaf(kC.x, xv, acc[i][8]);
            acc[i][9] = fmaf(kC.y, xv, acc[i][9]);
        }
        const float nw = xs[ph(ub + DDEP - 1 - d)];
        wn[3] = wn[2]; wn[2] = wn[1]; wn[1] = wn[0]; wn[0] = nw;
    }

    // ---- transpose via LDS (stride 11), then fully-coalesced float4 stores ----
    #pragma unroll
    for (int i = 0; i < 4; ++i)
        #pragma unroll
        for (int o = 0; o < OUTD; ++o)
            yb[(ub + i) * 11 + o] = acc[i][o];
    __syncthreads();

    float* yg = y + ((size_t)b * TLEN + t0) * OUTD;
    #pragma unroll
    for (int pass = 0; pass < 10; ++pass) {
        const int l2 = (pass * NTHR + tid) * 4;
        float4 v;
        v.x = yb[l2     + (l2    ) / 10];
        v.y = yb[l2 + 1 + (l2 + 1) / 10];
        v.z = yb[l2 + 2 + (l2 + 2) / 10];
        v.w = yb[l2 + 3 + (l2 + 3) / 10];
        *(float4*)(yg + l2) = v;
    }
}

extern "C" void kernel_launch(void* const* d_in, const int* in_sizes, int n_in,
                              void* d_out, int out_size, void* d_ws, size_t ws_size,
                              hipStream_t stream)
{
    const float* x  = (const float*)d_in[0];   // (64, 8192)
    const float* w1 = (const float*)d_in[1];   // (256, 1) contiguous
    const float* W2 = (const float*)d_in[2];   // (256, 256)
    const float* W3 = (const float*)d_in[3];   // (10, 256)
    float* y  = (float*)d_out;

    fused_rnn_kernel<<<NBLK, dim3(NTHR), 0, stream>>>(x, w1, W2, W3, y);
}

// Round 14
// 23.379 us; speedup vs baseline: 1.7301x; 1.1763x over previous
//
#include <hip/hip_runtime.h>

#define Hd    256
#define OUTD  10
#define DDEP  10
#define KSTR  12
#define TLEN  8192
#define NTHR  1024
#define NBLK  256
#define TILE  2048

typedef __attribute__((ext_vector_type(8))) short bf16x8;
typedef __attribute__((ext_vector_type(4))) float f32x4;

__device__ __forceinline__ int ph(int j) { return j + (j >> 5); }

// bf16 round-to-nearest-even helpers (no NaN in this data)
__device__ __forceinline__ unsigned bfr(float x) {
    unsigned u = __float_as_uint(x);
    return (u + 0x7FFFu + ((u >> 16) & 1u)) >> 16;
}
__device__ __forceinline__ unsigned bfpk(float lo, float hi) {
    unsigned uh = __float_as_uint(hi);
    unsigned h  = (uh + 0x7FFFu + ((uh >> 16) & 1u)) & 0xFFFF0000u;
    return bfr(lo) | h;
}

// LDS float/u32 offsets (r13-proven map):
//  [0, 32768)      W2h: W2 bf16 [256 rows][128 u32, XOR-swizzled]; yb aliases after A-frag build
//  [32768, 35328)  Vs fp32 [10][256] chain history
//  [35328, 37888)  W3s [10][256]
//  [37888, 38144)  Vbf [2][128] u32 bf16-pair ping-pong
//  [38144, 38272)  Ks [10][12] (+pad)
//  [38272, ...)    xs conv window (swizzled)
#define OFF_W2H 0
#define OFF_VS  32768
#define OFF_W3  35328
#define OFF_VBF 37888
#define OFF_KS  38144
#define OFF_XS  38272
#define XS_LOG  (TILE + DDEP)
#define SMEM_FLOATS (OFF_XS + XS_LOG + (XS_LOG >> 5) + 4)   // 161592 B < 160 KiB

__global__ __launch_bounds__(NTHR, 1) void fused_rnn_kernel(
    const float* __restrict__ x, const float* __restrict__ w1g,
    const float* __restrict__ W2, const float* __restrict__ W3,
    float* __restrict__ y)
{
    __shared__ float smem[SMEM_FLOATS];
    float* yb  = smem;                               // aliases W2h (epilogue only)
    unsigned* W2u = (unsigned*)(smem + OFF_W2H);
    float* Vs  = smem + OFF_VS;
    float* W3s = smem + OFF_W3;
    unsigned* Vbf = (unsigned*)(smem + OFF_VBF);
    float* Ks  = smem + OFF_KS;
    float* xs  = smem + OFF_XS;

    const int tid = threadIdx.x;
    const int bid = blockIdx.x;
    const int b   = bid >> 2;
    const int t0  = (bid & 3) * TILE;
    const float* xb = x + b * TLEN;

    // ---- stage W2 -> bf16 LDS (coalesced float4 reads; 16 iters/thread) ----
    const float4* W2v4 = (const float4*)W2;
    for (int g = tid; g < 16384; g += NTHR) {
        const float4 f = W2v4[g];
        const int row  = g >> 6;
        const int c    = (g & 63) * 2;               // u32 col (even)
        const int phys = c ^ ((row & 7) << 2);       // XOR-swizzle bits 2..4
        *(uint2*)&W2u[row * 128 + phys] =
            make_uint2(bfpk(f.x, f.y), bfpk(f.z, f.w));
    }

    // ---- stage xs (swizzled), W3s, v0 (fp32 + bf16) ----
    for (int j = tid; j < XS_LOG; j += NTHR) {
        const int g = t0 - DDEP + j;
        xs[ph(j)] = (g >= 0) ? xb[g] : 0.0f;
    }
    for (int i = tid; i < OUTD * Hd; i += NTHR) W3s[i] = W3[i];
    if (tid < Hd) Vs[tid] = w1g[tid];
    if (tid < 128) Vbf[tid] = bfpk(w1g[2 * tid], w1g[2 * tid + 1]);
    __syncthreads();

    // ---- build A-frags from LDS: wave w owns rows [16w, 16w+16) ----
    const int w = tid >> 6, l = tid & 63;
    bf16x8 Afr[8];
    {
        const int row = 16 * w + (l & 15);
        #pragma unroll
        for (int kt = 0; kt < 8; ++kt) {
            const int c    = kt * 16 + (l >> 4) * 4;       // u32 col, 4-aligned
            const int phys = c ^ ((row & 7) << 2);
            Afr[kt] = __builtin_bit_cast(bf16x8,
                *(const int4*)&W2u[row * 128 + phys]);
        }
    }
    __syncthreads();       // W2h dead from here; yb may overwrite later

    // ---- chain: v_{d+1} = W2 * v_d, 9 serial MFMA iterations ----
    #pragma unroll 1
    for (int d = 0; d < DDEP - 1; ++d) {
        const unsigned* vbf = Vbf + (d & 1) * 128;
        f32x4 acc = {0.f, 0.f, 0.f, 0.f};
        #pragma unroll
        for (int kt = 0; kt < 8; ++kt) {
            const bf16x8 Bfr = __builtin_bit_cast(bf16x8,
                *(const int4*)&vbf[kt * 16 + (l >> 4) * 4]);
            acc = __builtin_amdgcn_mfma_f32_16x16x32_bf16(Afr[kt], Bfr, acc, 0, 0, 0);
        }
        // C layout: col = lane&15, row = (lane>>4)*4 + reg (m89-verified)
        if ((l & 15) == 0) {
            const int r0 = 16 * w + 4 * (l >> 4);
            *(f32x4*)&Vs[(d + 1) * Hd + r0] = acc;
            *(uint2*)&Vbf[((d + 1) & 1) * 128 + (r0 >> 1)] =
                make_uint2(bfpk(acc.x, acc.y), bfpk(acc.z, acc.w));
        }
        __syncthreads();
    }

    // ---- K[d][o] = W3[o] . v_d : wave w handles d = w (w < 10) ----
    if (w < DDEP) {
        const int d = w;
        const float4 vv = ((const float4*)(Vs + d * Hd))[l];
        #pragma unroll
        for (int o = 0; o < OUTD; ++o) {
            const float4 wv = ((const float4*)(W3s + o * Hd))[l];
            float p = fmaf(wv.x, vv.x,
                      fmaf(wv.y, vv.y,
                      fmaf(wv.z, vv.z, wv.w * vv.w)));
            p += __shfl_xor(p, 1);  p += __shfl_xor(p, 2);
            p += __shfl_xor(p, 4);  p += __shfl_xor(p, 8);
            p += __shfl_xor(p, 16); p += __shfl_xor(p, 32);
            if (l == 0) Ks[d * KSTR + o] = p;
        }
        if (l == 1) { Ks[d * KSTR + 10] = 0.f; Ks[d * KSTR + 11] = 0.f; }
    }
    __syncthreads();

    // ---- causal FIR: 2 consecutive positions per thread ----
    const int ub = tid * 2;
    float acc0[OUTD], acc1[OUTD];
    #pragma unroll
    for (int o = 0; o < OUTD; ++o) { acc0[o] = 0.f; acc1[o] = 0.f; }

    float wn0 = xs[ph(ub + DDEP)];
    float wn1 = xs[ph(ub + DDEP + 1)];

    #pragma unroll
    for (int d = 0; d < DDEP; ++d) {
        const float4 kA = *(const float4*)&Ks[d * KSTR];
        const float4 kB = *(const float4*)&Ks[d * KSTR + 4];
        const float2 kC = *(const float2*)&Ks[d * KSTR + 8];
        acc0[0] = fmaf(kA.x, wn0, acc0[0]);  acc1[0] = fmaf(kA.x, wn1, acc1[0]);
        acc0[1] = fmaf(kA.y, wn0, acc0[1]);  acc1[1] = fmaf(kA.y, wn1, acc1[1]);
        acc0[2] = fmaf(kA.z, wn0, acc0[2]);  acc1[2] = fmaf(kA.z, wn1, acc1[2]);
        acc0[3] = fmaf(kA.w, wn0, acc0[3]);  acc1[3] = fmaf(kA.w, wn1, acc1[3]);
        acc0[4] = fmaf(kB.x, wn0, acc0[4]);  acc1[4] = fmaf(kB.x, wn1, acc1[4]);
        acc0[5] = fmaf(kB.y, wn0, acc0[5]);  acc1[5] = fmaf(kB.y, wn1, acc1[5]);
        acc0[6] = fmaf(kB.z, wn0, acc0[6]);  acc1[6] = fmaf(kB.z, wn1, acc1[6]);
        acc0[7] = fmaf(kB.w, wn0, acc0[7]);  acc1[7] = fmaf(kB.w, wn1, acc1[7]);
        acc0[8] = fmaf(kC.x, wn0, acc0[8]);  acc1[8] = fmaf(kC.x, wn1, acc1[8]);
        acc0[9] = fmaf(kC.y, wn0, acc0[9]);  acc1[9] = fmaf(kC.y, wn1, acc1[9]);
        wn1 = wn0;
        wn0 = xs[ph(ub + DDEP - 1 - d)];
    }

    // ---- transpose via LDS (stride 11), then fully-coalesced float4 stores ----
    #pragma unroll
    for (int o = 0; o < OUTD; ++o) {
        yb[ub * 11 + o]      = acc0[o];
        yb[ub * 11 + 11 + o] = acc1[o];
    }
    __syncthreads();

    float* yg = y + ((size_t)b * TLEN + t0) * OUTD;
    #pragma unroll
    for (int pass = 0; pass < 5; ++pass) {
        const int l2 = (pass * NTHR + tid) * 4;
        float4 v;
        v.x = yb[l2     + (l2    ) / 10];
        v.y = yb[l2 + 1 + (l2 + 1) / 10];
        v.z = yb[l2 + 2 + (l2 + 2) / 10];
        v.w = yb[l2 + 3 + (l2 + 3) / 10];
        *(float4*)(yg + l2) = v;
    }
}

extern "C" void kernel_launch(void* const* d_in, const int* in_sizes, int n_in,
                              void* d_out, int out_size, void* d_ws, size_t ws_size,
                              hipStream_t stream)
{
    const float* x  = (const float*)d_in[0];   // (64, 8192)
    const float* w1 = (const float*)d_in[1];   // (256, 1) contiguous
    const float* W2 = (const float*)d_in[2];   // (256, 256)
    const float* W3 = (const float*)d_in[3];   // (10, 256)
    float* y  = (float*)d_out;

    fused_rnn_kernel<<<NBLK, dim3(NTHR), 0, stream>>>(x, w1, W2, W3, y);
}

// Round 16
// 22.759 us; speedup vs baseline: 1.7771x; 1.0272x over previous
//
#include <hip/hip_runtime.h>

#define Hd    256
#define OUTD  10
#define DDEP  10
#define KSTR  12
#define TLEN  8192
#define NTHR  1024
#define NBLK  256
#define TILE  2048

typedef __attribute__((ext_vector_type(8))) short bf16x8;
typedef __attribute__((ext_vector_type(4))) float f32x4;

__device__ __forceinline__ int ph(int j) { return j + (j >> 5); }

// bf16 round-to-nearest-even helpers (no NaN in this data)
__device__ __forceinline__ unsigned bfr(float x) {
    unsigned u = __float_as_uint(x);
    return (u + 0x7FFFu + ((u >> 16) & 1u)) >> 16;
}
__device__ __forceinline__ unsigned bfpk(float lo, float hi) {
    unsigned uh = __float_as_uint(hi);
    unsigned h  = (uh + 0x7FFFu + ((uh >> 16) & 1u)) & 0xFFFF0000u;
    return bfr(lo) | h;
}

// LDS float/u32 offsets (r13/r14-proven map):
//  [0, 32768)      W2h: W2 bf16 [256 rows][128 u32, XOR-swizzled]; yb aliases after A-frag build
//  [32768, 35328)  Vs fp32 [10][256] chain history
//  [35328, 37888)  W3s [10][256]
//  [37888, 38144)  Vbf [2][128] u32 bf16-pair ping-pong
//  [38144, 38272)  Ks [10][12] (+pad)
//  [38272, ...)    xs conv window (swizzled)
#define OFF_W2H 0
#define OFF_VS  32768
#define OFF_W3  35328
#define OFF_VBF 37888
#define OFF_KS  38144
#define OFF_XS  38272
#define XS_LOG  (TILE + DDEP)
#define SMEM_FLOATS (OFF_XS + XS_LOG + (XS_LOG >> 5) + 4)   // 161592 B < 160 KiB

__global__ __launch_bounds__(NTHR, 1) void fused_rnn_kernel(
    const float* __restrict__ x, const float* __restrict__ w1g,
    const float* __restrict__ W2, const float* __restrict__ W3,
    float* __restrict__ y)
{
    __shared__ float smem[SMEM_FLOATS];
    float* yb  = smem;                               // aliases W2h (epilogue only)
    unsigned* W2u = (unsigned*)(smem + OFF_W2H);
    float* Vs  = smem + OFF_VS;
    float* W3s = smem + OFF_W3;
    unsigned* Vbf = (unsigned*)(smem + OFF_VBF);
    float* Ks  = smem + OFF_KS;
    float* xs  = smem + OFF_XS;

    const int tid = threadIdx.x;
    const int bid = blockIdx.x;
    const int b   = bid >> 2;
    const int t0  = (bid & 3) * TILE;
    const float* xb = x + b * TLEN;

    // ---- stage W2 -> bf16 LDS (coalesced float4 reads; 16 iters/thread) ----
    const float4* W2v4 = (const float4*)W2;
    for (int g = tid; g < 16384; g += NTHR) {
        const float4 f = W2v4[g];
        const int row  = g >> 6;
        const int c    = (g & 63) * 2;               // u32 col (even)
        const int phys = c ^ ((row & 7) << 2);       // XOR-swizzle bits 2..4
        *(uint2*)&W2u[row * 128 + phys] =
            make_uint2(bfpk(f.x, f.y), bfpk(f.z, f.w));
    }

    // ---- stage xs (swizzled), W3s, v0 (fp32 + bf16) ----
    for (int j = tid; j < XS_LOG; j += NTHR) {
        const int g = t0 - DDEP + j;
        xs[ph(j)] = (g >= 0) ? xb[g] : 0.0f;
    }
    for (int i = tid; i < OUTD * Hd; i += NTHR) W3s[i] = W3[i];
    if (tid < Hd) Vs[tid] = w1g[tid];
    if (tid < 128) Vbf[tid] = bfpk(w1g[2 * tid], w1g[2 * tid + 1]);
    __syncthreads();

    // ---- build A-frags from LDS: chain waves 0-7, wave w owns rows [32w, 32w+32) ----
    const int w = tid >> 6, l = tid & 63;
    bf16x8 Afr[2][8];
    if (w < 8) {
        #pragma unroll
        for (int rt = 0; rt < 2; ++rt) {
            const int row = 32 * w + 16 * rt + (l & 15);
            #pragma unroll
            for (int kt = 0; kt < 8; ++kt) {
                const int c    = kt * 16 + (l >> 4) * 4;   // u32 col, 4-aligned
                const int phys = c ^ ((row & 7) << 2);
                Afr[rt][kt] = __builtin_bit_cast(bf16x8,
                    *(const int4*)&W2u[row * 128 + phys]);
            }
        }
    }
    __syncthreads();       // W2h dead from here; yb may overwrite later

    // ---- chain: v_{d+1} = W2 * v_d, 9 serial MFMA iterations (8 waves, r13 layout) ----
    #pragma unroll 1
    for (int d = 0; d < DDEP - 1; ++d) {
        if (w < 8) {
            const unsigned* vbf = Vbf + (d & 1) * 128;
            f32x4 acc0 = {0.f, 0.f, 0.f, 0.f};
            f32x4 acc1 = {0.f, 0.f, 0.f, 0.f};
            #pragma unroll
            for (int kt = 0; kt < 8; ++kt) {
                const bf16x8 Bfr = __builtin_bit_cast(bf16x8,
                    *(const int4*)&vbf[kt * 16 + (l >> 4) * 4]);
                acc0 = __builtin_amdgcn_mfma_f32_16x16x32_bf16(Afr[0][kt], Bfr, acc0, 0, 0, 0);
                acc1 = __builtin_amdgcn_mfma_f32_16x16x32_bf16(Afr[1][kt], Bfr, acc1, 0, 0, 0);
            }
            // C layout: col = lane&15, row = (lane>>4)*4 + reg (m89-verified)
            if ((l & 15) == 0) {
                const int g  = l >> 4;
                const int r0 = 32 * w + 4 * g;
                const int r1 = r0 + 16;
                *(f32x4*)&Vs[(d + 1) * Hd + r0] = acc0;
                *(f32x4*)&Vs[(d + 1) * Hd + r1] = acc1;
                unsigned* dst = Vbf + ((d + 1) & 1) * 128;
                *(uint2*)&dst[r0 >> 1] =
                    make_uint2(bfpk(acc0.x, acc0.y), bfpk(acc0.z, acc0.w));
                *(uint2*)&dst[r1 >> 1] =
                    make_uint2(bfpk(acc1.x, acc1.y), bfpk(acc1.z, acc1.w));
            }
        }
        __syncthreads();
    }

    // ---- K[d][o] = W3[o] . v_d : wave w handles d = w (w < 10) ----
    if (w < DDEP) {
        const int d = w;
        const float4 vv = ((const float4*)(Vs + d * Hd))[l];
        #pragma unroll
        for (int o = 0; o < OUTD; ++o) {
            const float4 wv = ((const float4*)(W3s + o * Hd))[l];
            float p = fmaf(wv.x, vv.x,
                      fmaf(wv.y, vv.y,
                      fmaf(wv.z, vv.z, wv.w * vv.w)));
            p += __shfl_xor(p, 1);  p += __shfl_xor(p, 2);
            p += __shfl_xor(p, 4);  p += __shfl_xor(p, 8);
            p += __shfl_xor(p, 16); p += __shfl_xor(p, 32);
            if (l == 0) Ks[d * KSTR + o] = p;
        }
        if (l == 1) { Ks[d * KSTR + 10] = 0.f; Ks[d * KSTR + 11] = 0.f; }
    }
    __syncthreads();

    // ---- causal FIR: 2 consecutive positions per thread ----
    const int ub = tid * 2;
    float acc0[OUTD], acc1[OUTD];
    #pragma unroll
    for (int o = 0; o < OUTD; ++o) { acc0[o] = 0.f; acc1[o] = 0.f; }

    float wn0 = xs[ph(ub + DDEP)];
    float wn1 = xs[ph(ub + DDEP + 1)];

    #pragma unroll
    for (int d = 0; d < DDEP; ++d) {
        const float4 kA = *(const float4*)&Ks[d * KSTR];
        const float4 kB = *(const float4*)&Ks[d * KSTR + 4];
        const float2 kC = *(const float2*)&Ks[d * KSTR + 8];
        acc0[0] = fmaf(kA.x, wn0, acc0[0]);  acc1[0] = fmaf(kA.x, wn1, acc1[0]);
        acc0[1] = fmaf(kA.y, wn0, acc0[1]);  acc1[1] = fmaf(kA.y, wn1, acc1[1]);
        acc0[2] = fmaf(kA.z, wn0, acc0[2]);  acc1[2] = fmaf(kA.z, wn1, acc1[2]);
        acc0[3] = fmaf(kA.w, wn0, acc0[3]);  acc1[3] = fmaf(kA.w, wn1, acc1[3]);
        acc0[4] = fmaf(kB.x, wn0, acc0[4]);  acc1[4] = fmaf(kB.x, wn1, acc1[4]);
        acc0[5] = fmaf(kB.y, wn0, acc0[5]);  acc1[5] = fmaf(kB.y, wn1, acc1[5]);
        acc0[6] = fmaf(kB.z, wn0, acc0[6]);  acc1[6] = fmaf(kB.z, wn1, acc1[6]);
        acc0[7] = fmaf(kB.w, wn0, acc0[7]);  acc1[7] = fmaf(kB.w, wn1, acc1[7]);
        acc0[8] = fmaf(kC.x, wn0, acc0[8]);  acc1[8] = fmaf(kC.x, wn1, acc1[8]);
        acc0[9] = fmaf(kC.y, wn0, acc0[9]);  acc1[9] = fmaf(kC.y, wn1, acc1[9]);
        wn1 = wn0;
        wn0 = xs[ph(ub + DDEP - 1 - d)];
    }

    // ---- transpose via LDS (stride 11), then coalesced nontemporal stores ----
    #pragma unroll
    for (int o = 0; o < OUTD; ++o) {
        yb[ub * 11 + o]      = acc0[o];
        yb[ub * 11 + 11 + o] = acc1[o];
    }
    __syncthreads();

    float* yg = y + ((size_t)b * TLEN + t0) * OUTD;
    #pragma unroll
    for (int pass = 0; pass < 5; ++pass) {
        const int l2 = (pass * NTHR + tid) * 4;
        f32x4 v;
        v.x = yb[l2     + (l2    ) / 10];
        v.y = yb[l2 + 1 + (l2 + 1) / 10];
        v.z = yb[l2 + 2 + (l2 + 2) / 10];
        v.w = yb[l2 + 3 + (l2 + 3) / 10];
        __builtin_nontemporal_store(v, (f32x4*)(yg + l2));
    }
}

extern "C" void kernel_launch(void* const* d_in, const int* in_sizes, int n_in,
                              void* d_out, int out_size, void* d_ws, size_t ws_size,
                              hipStream_t stream)
{
    const float* x  = (const float*)d_in[0];   // (64, 8192)
    const float* w1 = (const float*)d_in[1];   // (256, 1) contiguous
    const float* W2 = (const float*)d_in[2];   // (256, 256)
    const float* W3 = (const float*)d_in[3];   // (10, 256)
    float* y  = (float*)d_out;

    fused_rnn_kernel<<<NBLK, dim3(NTHR), 0, stream>>>(x, w1, W2, W3, y);
}